// Round 11
// baseline (636.008 us; speedup 1.0000x reference)
//
#include <hip/hip_runtime.h>
#include <math.h>

#define NN    8192      // nodes
#define PP    3         // meta-paths
#define INF_  256       // input features
#define HID_  64
#define HEADS 8
#define OUTF  64
#define NE    262144    // edges per path (2^18)
#define HD    512       // HEADS*HID
#define DEGCAP 128      // multinomial(262144,8192): mean 32, max ~70; 128 is 16 sigma
// src-bucketed dst-CSR: 4 buckets of 2048 src nodes (2 MB featb/path/bucket —
// proven optimum; NB=8 regressed). counts/cursor: [3 paths][NN dst][4 buckets].
// No src-CSR: atten built column-wise (LDS colbuf + plain scattered stores).
#define NB    4
#define DOFF  (NB * NN)         // per-path dst-bucket bin count
#define POFF  (NB * NN + 1)     // per-path offsets stride

typedef __attribute__((ext_vector_type(8))) short short8;
typedef __attribute__((ext_vector_type(4))) float f32x4;

// round-to-nearest-even fp32 -> bf16
__device__ __forceinline__ unsigned short f2bf(float f) {
    unsigned u = __float_as_uint(f);
    unsigned r = u + 0x7fffu + ((u >> 16) & 1u);
    return (unsigned short)(r >> 16);
}
__device__ __forceinline__ float bf2f_lo(unsigned v) { return __uint_as_float(v << 16); }
__device__ __forceinline__ float bf2f_hi(unsigned v) { return __uint_as_float(v & 0xffff0000u); }

// beta from wsum bins — register-only (identical fp32 sequence everywhere)
__device__ __forceinline__ void beta_reg(const float* __restrict__ wsum,
                                         float& rb0, float& rb1, float& rb2) {
    int lane = threadIdx.x & 63;
    float s0 = wsum[lane], s1 = wsum[64 + lane], s2 = wsum[128 + lane];
#pragma unroll
    for (int off = 32; off > 0; off >>= 1) {
        s0 += __shfl_down(s0, off);
        s1 += __shfl_down(s1, off);
        s2 += __shfl_down(s2, off);
    }
    float t0 = __shfl(s0, 0), t1 = __shfl(s1, 0), t2 = __shfl(s2, 0);
    float w0 = t0 / (float)NN, w1 = t1 / (float)NN, w2 = t2 / (float)NN;
    float m  = fmaxf(w0, fmaxf(w1, w2));
    float e0 = expf(w0 - m), e1 = expf(w1 - m), e2 = expf(w2 - m);
    float ss = e0 + e1 + e2;
    rb0 = e0 / ss; rb1 = e1 / ss; rb2 = e2 / ss;
}

// ---- K0: cast h->bf16, cast+transpose fc->fcT, dst-bucket histogram,
//          zero atten (256 MB NT stores, overlapped with atomic-bound blocks) ----
__global__ __launch_bounds__(256) void cast_count(
        const float* __restrict__ h, const float* __restrict__ fc,
        const int* __restrict__ esrc, const int* __restrict__ edst,
        unsigned short* __restrict__ hb, unsigned short* __restrict__ fcT,
        int* __restrict__ counts /* [3][NN][NB] */,
        float* __restrict__ atten) {
    int b = blockIdx.x, t = threadIdx.x;
    if (b < 2048) {                               // h: 2M elems, float4
        int i = b * 256 + t;
        float4 v = *(const float4*)(h + (size_t)i * 4);
        ushort4 o = { f2bf(v.x), f2bf(v.y), f2bf(v.z), f2bf(v.w) };
        *(ushort4*)(hb + (size_t)i * 4) = o;
    } else if (b < 2048 + 1536) {                 // fc: 393216 elems, transpose
        int i = (b - 2048) * 256 + t;
        if (i < PP * INF_ * HD) {
            int p = i / (INF_ * HD);
            int rem = i - p * INF_ * HD;
            int k = rem / HD;
            int n = rem - k * HD;
            fcT[(size_t)p * HD * INF_ + (size_t)n * INF_ + k] = f2bf(fc[i]);
        }
    } else if (b < 2048 + 1536 + 768) {           // edges: 4/thread, int4 loads
        int i = (b - 3584) * 256 + t;             // < 196608 (= PP*NE/4)
        int4 s4 = ((const int4*)esrc)[i];
        int4 d4 = ((const int4*)edst)[i];
        int p = i >> 16;                          // 65536 int4-groups per path
        int base = p * DOFF;
        atomicAdd(&counts[base + (d4.x << 2) + (s4.x >> 11)], 1);
        atomicAdd(&counts[base + (d4.y << 2) + (s4.y >> 11)], 1);
        atomicAdd(&counts[base + (d4.z << 2) + (s4.z >> 11)], 1);
        atomicAdd(&counts[base + (d4.w << 2) + (s4.w >> 11)], 1);
    } else {                                      // zero atten: 1024 blocks
        f32x4* a4 = (f32x4*)atten;                // 16777216 f32x4 total
        int idx0 = (b - 4352) * 256 + t;          // [0, 262144)
        f32x4 zero = {0.f, 0.f, 0.f, 0.f};
#pragma unroll 4
        for (int it = 0; it < 64; ++it)
            __builtin_nontemporal_store(zero, &a4[(size_t)it * 262144 + idx0]);
    }
}

// ---- K1: exclusive scans — blocks 0..2: dst-bucketed (32768 bins, 32/thread);
//          block 3: collapsed semantic vec ----
__global__ __launch_bounds__(1024) void scan_vw(
        const int* __restrict__ counts, int* __restrict__ offsets,
        int* __restrict__ cursor, const float* __restrict__ w1,
        const float* __restrict__ b1, const float* __restrict__ w2,
        float* __restrict__ v /* [513] */) {
    int t = threadIdx.x;
    if (blockIdx.x == 3) {
        if (t < HD) {
            float s = 0.f;
            for (int k = 0; k < 128; ++k) s += w1[t * 128 + k] * w2[k];
            v[t] = s;
        } else if (t == HD) {
            float c = 0.f;
            for (int k = 0; k < 128; ++k) c += b1[k] * w2[k];
            v[HD] = c;
        }
        return;
    }
    __shared__ int sh[1024];
    // dst-bucketed segment for path seg: 4*NN bins, 32 per thread
    int seg = blockIdx.x;
    const int* cnt = counts + seg * DOFF;
    int* offs = offsets + seg * POFF;
    int* cur  = cursor + seg * DOFF;
    int loc[32];
    int s = 0;
#pragma unroll
    for (int i = 0; i < 32; ++i) { loc[i] = cnt[t * 32 + i]; s += loc[i]; }
    sh[t] = s;
    __syncthreads();
    for (int off = 1; off < 1024; off <<= 1) {
        int vv = (t >= off) ? sh[t - off] : 0;
        __syncthreads();
        sh[t] += vv;
        __syncthreads();
    }
    int run = sh[t] - s;
#pragma unroll
    for (int i = 0; i < 32; ++i) {
        offs[t * 32 + i] = run;
        cur[t * 32 + i]  = run;
        run += loc[i];
    }
    if (t == 1023) offs[DOFF] = run;
}

// ---- K23: MERGED scatter (blocks 0..3071) + feat GEMM (blocks 3072..6143) ----
// Scatter: 1 global atomic + 1 store per edge (measured-cheap at this
// parallelism; R7's serial atomic-free variant was 4x worse).
#define LDK 72   // padded LDS row stride (bf16)
__global__ __launch_bounds__(256) void scatter_gemm(
        const int* __restrict__ esrc, const int* __restrict__ edst,
        int* __restrict__ cursor, int* __restrict__ ssrc_sorted,
        const unsigned short* __restrict__ hb,   // [NN, INF_] bf16
        const unsigned short* __restrict__ fcT,  // [PP, HD, INF_] bf16
        const float* __restrict__ al_all,        // [PP, HD]
        const float* __restrict__ ar_all,        // [PP, HD]
        unsigned short* __restrict__ featb,      // [PP, NN, HD] bf16
        float* __restrict__ el,                  // [PP, NN, HEADS]
        float* __restrict__ er) {
    __shared__ unsigned short As[64 * LDK];
    __shared__ unsigned short Bs[64 * LDK];
    int tid = threadIdx.x;
    if (blockIdx.x < 3072) {
        // ---- scatter role: bucketed dst-CSR (src values) ----
        int i = blockIdx.x * 256 + tid;          // exactly PP*NE threads
        int p = i >> 18;
        int s = esrc[i], d = edst[i];
        int pos = atomicAdd(&cursor[p * DOFF + (d << 2) + (s >> 11)], 1);
        ssrc_sorted[(size_t)p * NE + pos] = s;
        return;
    }
    // ---- GEMM role: feat[p] = h @ fc_p via bf16 MFMA; K-stage 64 ----
    int g  = blockIdx.x - 3072;                  // 0..3071
    int p  = g >> 10;                            // 1024 blocks per path
    int n0 = (g & 7) * 64;
    int m0 = ((g >> 3) & 127) * 64;
    const unsigned short* Bt = fcT + (size_t)p * HD * INF_;
    unsigned short* C = featb + (size_t)p * NN * HD;
    int wv   = tid >> 6, lane = tid & 63;
    int row  = tid >> 2, kc = (tid & 3) * 8;     // staging: 64 rows x 32 k (x2 chunks)
    int l16  = lane & 15, quad = lane >> 4;
    int mw   = wv * 16;
    f32x4 acc[4] = {{0.f,0.f,0.f,0.f},{0.f,0.f,0.f,0.f},
                    {0.f,0.f,0.f,0.f},{0.f,0.f,0.f,0.f}};
    for (int k0 = 0; k0 < INF_; k0 += 64) {
        const unsigned short* ha = &hb[(size_t)(m0 + row) * INF_ + k0 + kc];
        const unsigned short* ba = &Bt[(size_t)(n0 + row) * INF_ + k0 + kc];
        *(short8*)&As[row * LDK + kc]      = *(const short8*)ha;
        *(short8*)&As[row * LDK + kc + 32] = *(const short8*)(ha + 32);
        *(short8*)&Bs[row * LDK + kc]      = *(const short8*)ba;
        *(short8*)&Bs[row * LDK + kc + 32] = *(const short8*)(ba + 32);
        __syncthreads();
        short8 af0 = *(short8*)&As[(mw + l16) * LDK + quad * 8];
        short8 af1 = *(short8*)&As[(mw + l16) * LDK + 32 + quad * 8];
#pragma unroll
        for (int nt = 0; nt < 4; ++nt) {
            short8 bf0 = *(short8*)&Bs[(nt * 16 + l16) * LDK + quad * 8];
            acc[nt] = __builtin_amdgcn_mfma_f32_16x16x32_bf16(af0, bf0, acc[nt], 0, 0, 0);
            short8 bf1 = *(short8*)&Bs[(nt * 16 + l16) * LDK + 32 + quad * 8];
            acc[nt] = __builtin_amdgcn_mfma_f32_16x16x32_bf16(af1, bf1, acc[nt], 0, 0, 0);
        }
        __syncthreads();
    }
    // D layout: col = nt*16 + l16, row = mw + quad*4 + r
#pragma unroll
    for (int nt = 0; nt < 4; ++nt) {
#pragma unroll
        for (int r = 0; r < 4; ++r) {
            C[(size_t)(m0 + mw + quad * 4 + r) * HD + n0 + nt * 16 + l16] =
                f2bf(acc[nt][r]);
        }
    }
    // fused el/er: head h = n0/64 fully contained in this block's n-tile
    int hidx = n0 >> 6;
    float alv[4], arv[4];
#pragma unroll
    for (int nt = 0; nt < 4; ++nt) {
        alv[nt] = al_all[p * HD + n0 + nt * 16 + l16];
        arv[nt] = ar_all[p * HD + n0 + nt * 16 + l16];
    }
    float* elp = el + (size_t)p * NN * HEADS;
    float* erp = er + (size_t)p * NN * HEADS;
#pragma unroll
    for (int r = 0; r < 4; ++r) {
        float pe = acc[0][r] * alv[0] + acc[1][r] * alv[1] +
                   acc[2][r] * alv[2] + acc[3][r] * alv[3];
        float pr = acc[0][r] * arv[0] + acc[1][r] * arv[1] +
                   acc[2][r] * arv[2] + acc[3][r] * arv[3];
#pragma unroll
        for (int m = 1; m < 16; m <<= 1) {
            pe += __shfl_xor(pe, m);
            pr += __shfl_xor(pr, m);
        }
        if (l16 == 0) {
            int node = m0 + mw + quad * 4 + r;
            elp[node * HEADS + hidx] = pe;
            erp[node * HEADS + hidx] = pr;
        }
    }
}

// ---- K4: FUSED edge softmax + aggregation, ONE WAVE PER (dst,p) ----
// XCD-aware swizzle: each XCD owns a contiguous gid range, so its waves walk
// the same featb bucket slice together -> slice stays in that XCD's 4MB L2.
__global__ __launch_bounds__(256) void fused_attn_rst(
        const int* __restrict__ ssrc_sorted, const int* __restrict__ offsets_all,
        const float* __restrict__ el, const float* __restrict__ er,
        const unsigned short* __restrict__ featb,
        const float* __restrict__ bias_all, const float* __restrict__ v,
        float* __restrict__ alpha_all /* dst-sorted order */,
        unsigned short* __restrict__ zpb,
        float* __restrict__ wsum /* [3][64] bins */) {
    __shared__ float sh_e[4][DEGCAP * 8];
    __shared__ int   sh_src[4][DEGCAP];
    int wv = threadIdx.x >> 6, lane = threadIdx.x & 63;
    // bijective XCD swizzle: nwg = 6144 = 8 * 768
    int swz = (blockIdx.x & 7) * 768 + (blockIdx.x >> 3);
    int gid = swz * 4 + wv;                // over NN*PP
    int n = gid & (NN - 1);
    int p = gid >> 13;                     // NN = 2^13
    const int* srcrow  = ssrc_sorted + (size_t)p * NE;
    const int* offs    = offsets_all + p * POFF;
    const float* elp   = el + (size_t)p * NN * HEADS;
    const float* erp   = er + (size_t)p * NN * HEADS;
    const unsigned short* feat = featb + (size_t)p * NN * HD;
    int start = offs[n * NB];
    int deg = offs[n * NB + NB] - start;   // whole (4-bucket) list for dst n
    if (deg > DEGCAP) deg = DEGCAP;        // 16-sigma safe

    // Phase A: one sequential src read per edge; leaky-relu scores into LDS
    float4 r0 = *(const float4*)(erp + n * 8);
    float4 r1 = *(const float4*)(erp + n * 8 + 4);
    for (int t = lane; t < deg; t += 64) {
        int s = srcrow[start + t];
        sh_src[wv][t] = s;
        float4 l0 = *(const float4*)(elp + s * 8);
        float4 l1 = *(const float4*)(elp + s * 8 + 4);
        float sc[8] = {l0.x + r0.x, l0.y + r0.y, l0.z + r0.z, l0.w + r0.w,
                       l1.x + r1.x, l1.y + r1.y, l1.z + r1.z, l1.w + r1.w};
#pragma unroll
        for (int hh = 0; hh < 8; ++hh) {
            float x = sc[hh];
            sh_e[wv][t * 8 + hh] = x > 0.f ? x : 0.2f * x;
        }
    }
    __syncthreads();

    // Phase B: per-head softmax; 8 lanes per head (h = lane>>3, j = lane&7)
    int h = lane >> 3;
    {
        int j = lane & 7;
        float m = -INFINITY;
        for (int t = j; t < deg; t += 8) m = fmaxf(m, sh_e[wv][t * 8 + h]);
#pragma unroll
        for (int off = 4; off; off >>= 1) m = fmaxf(m, __shfl_xor(m, off));
        float ssum = 0.f;
        for (int t = j; t < deg; t += 8) {
            float ee = __expf(sh_e[wv][t * 8 + h] - m);
            sh_e[wv][t * 8 + h] = ee;
            ssum += ee;
        }
#pragma unroll
        for (int off = 4; off; off >>= 1) ssum += __shfl_xor(ssum, off);
        float inv = 1.f / ssum;
        for (int t = j; t < deg; t += 8) sh_e[wv][t * 8 + h] *= inv;
    }
    __syncthreads();

    // Phase C: alpha = mean over heads — fully coalesced write
    for (int t = lane; t < deg; t += 64) {
        float s = 0.f;
#pragma unroll
        for (int hh = 0; hh < 8; ++hh) s += sh_e[wv][t * 8 + hh];
        alpha_all[(size_t)p * NE + start + t] = s * 0.125f;
    }

    // Phase D: lane covers cols c..c+7 (head h); one 16B load per edge row.
    int c = lane * 8;
    float acc[8] = {0.f, 0.f, 0.f, 0.f, 0.f, 0.f, 0.f, 0.f};
#define FMA8(F, KI) { \
        float a_ = sh_e[wv][(KI) * 8 + h]; \
        acc[0] += a_ * bf2f_lo((F).x); acc[1] += a_ * bf2f_hi((F).x); \
        acc[2] += a_ * bf2f_lo((F).y); acc[3] += a_ * bf2f_hi((F).y); \
        acc[4] += a_ * bf2f_lo((F).z); acc[5] += a_ * bf2f_hi((F).z); \
        acc[6] += a_ * bf2f_lo((F).w); acc[7] += a_ * bf2f_hi((F).w); }
    int k = 0;
    for (; k + 4 <= deg; k += 4) {
        int s0 = sh_src[wv][k],     s1 = sh_src[wv][k + 1];
        int s2 = sh_src[wv][k + 2], s3 = sh_src[wv][k + 3];
        uint4 f0 = *(const uint4*)&feat[(size_t)s0 * HD + c];
        uint4 f1 = *(const uint4*)&feat[(size_t)s1 * HD + c];
        uint4 f2 = *(const uint4*)&feat[(size_t)s2 * HD + c];
        uint4 f3 = *(const uint4*)&feat[(size_t)s3 * HD + c];
        FMA8(f0, k); FMA8(f1, k + 1); FMA8(f2, k + 2); FMA8(f3, k + 3);
    }
    for (; k < deg; ++k) {
        int s = sh_src[wv][k];
        uint4 f = *(const uint4*)&feat[(size_t)s * HD + c];
        FMA8(f, k);
    }
#undef FMA8
    const float* bias = bias_all + p * HD;
    float4 b0 = *(const float4*)(bias + c);
    float4 b1 = *(const float4*)(bias + c + 4);
    float z[8];
    z[0] = acc[0] + b0.x; z[1] = acc[1] + b0.y; z[2] = acc[2] + b0.z; z[3] = acc[3] + b0.w;
    z[4] = acc[4] + b1.x; z[5] = acc[5] + b1.y; z[6] = acc[6] + b1.z; z[7] = acc[7] + b1.w;
#pragma unroll
    for (int i = 0; i < 8; ++i) z[i] = z[i] > 0.f ? z[i] : expm1f(z[i]);
    uint4 zo;
    zo.x = (unsigned)f2bf(z[0]) | ((unsigned)f2bf(z[1]) << 16);
    zo.y = (unsigned)f2bf(z[2]) | ((unsigned)f2bf(z[3]) << 16);
    zo.z = (unsigned)f2bf(z[4]) | ((unsigned)f2bf(z[5]) << 16);
    zo.w = (unsigned)f2bf(z[6]) | ((unsigned)f2bf(z[7]) << 16);
    *(uint4*)&zpb[(size_t)n * (PP * HD) + p * HD + c] = zo;

    // Phase E: semantic-attention partial — wave-reduce dot(z, v)
    float4 v0 = *(const float4*)(v + c);
    float4 v1 = *(const float4*)(v + c + 4);
    float part = z[0] * v0.x + z[1] * v0.y + z[2] * v0.z + z[3] * v0.w +
                 z[4] * v1.x + z[5] * v1.y + z[6] * v1.z + z[7] * v1.w;
#pragma unroll
    for (int off = 32; off > 0; off >>= 1) part += __shfl_down(part, off);
    if (lane == 0) {
        float w = part + v[HD];             // + c0
        w = w > 0.f ? w : 0.01f * w;        // leaky_relu 0.01 BEFORE mean
        atomicAdd(&wsum[p * 64 + (n & 63)], w);
    }
}

// ---- K56: atten COLUMN build + final_out, XCD-SWIZZLED block remap ----
// atten[s*NN + n]: 16 consecutive columns n share one 64B line. Swizzle gives
// each XCD a contiguous run of ~1088 columns, so concurrent blocks on one XCD
// write adjacent n -> partial-line stores merge in that XCD's L2 before one
// line writeback (instead of the same line dirtied in 8 incoherent L2s).
#define K5R 16
#define K56_NWG (NN + NN / K5R)   // 8704 = 8 * 1088
__global__ __launch_bounds__(256) void final_atten(
        const unsigned short* __restrict__ zpb, const float* __restrict__ wsum,
        const float* __restrict__ pw, const float* __restrict__ pb,
        const int* __restrict__ ssrc_sorted, const int* __restrict__ offsets_all,
        const float* __restrict__ alpha,
        float* __restrict__ out, float* __restrict__ atten) {
    __shared__ float buf[NN];          // 32 KB: colbuf (atten) or zt (out role)
    __shared__ int   sh_s[3 * DEGCAP];
    __shared__ int   sh_cnt;
    float b0, b1, b2;
    beta_reg(wsum, b0, b1, b2);
    int tid = threadIdx.x;
    // bijective XCD swizzle: 8704 = 8 * 1088
    int sbid = (blockIdx.x & 7) * 1088 + (blockIdx.x >> 3);
    if (sbid < NN) {
        // ---- atten-column role: dst n, all 3 paths ----
        int n = sbid;
        f32x4 zero = {0.f, 0.f, 0.f, 0.f};
        for (int j = tid; j < NN / 4; j += 256) ((f32x4*)buf)[j] = zero;
        if (tid == 0) sh_cnt = 0;
        __syncthreads();
        for (int p = 0; p < PP; ++p) {
            float bsel = p == 0 ? b0 : (p == 1 ? b1 : b2);
            const int* offs = offsets_all + p * POFF;
            int start = offs[n * NB];
            int deg = offs[n * NB + NB] - start;
            if (deg > DEGCAP) deg = DEGCAP;
            const int* srcrow = ssrc_sorted + (size_t)p * NE + start;   // sequential
            const float* arow = alpha + (size_t)p * NE + start;         // sequential
            for (int t = tid; t < deg; t += 256) {
                int s = srcrow[t];
                atomicAdd(&buf[s], arow[t] * bsel);      // LDS atomic (cheap)
                int slot = atomicAdd(&sh_cnt, 1);        // LDS counter
                sh_s[slot] = s;
            }
        }
        __syncthreads();
        int cnt = sh_cnt;
        for (int k = tid; k < cnt; k += 256) {
            int s = sh_s[k];
            __builtin_nontemporal_store(buf[s], &atten[(size_t)s * NN + n]);
        }
    } else {
        // ---- final_out role: 16 rows/block, pred_w streamed once per block ----
        float* zt = buf;                   // [K5R][HD] row-major
        int n0 = (sbid - NN) * K5R;
        int c = tid * 2;
#pragma unroll
        for (int r = 0; r < K5R; ++r) {
            const unsigned short* zr = zpb + (size_t)(n0 + r) * (PP * HD);
            unsigned u0 = *(const unsigned*)(zr + c);
            unsigned u1 = *(const unsigned*)(zr + HD + c);
            unsigned u2 = *(const unsigned*)(zr + 2 * HD + c);
            zt[r * HD + c]     = b0 * bf2f_lo(u0) + b1 * bf2f_lo(u1) + b2 * bf2f_lo(u2);
            zt[r * HD + c + 1] = b0 * bf2f_hi(u0) + b1 * bf2f_hi(u1) + b2 * bf2f_hi(u2);
        }
        __syncthreads();
        int o = tid & 63, rg = tid >> 6;   // 4 row-groups x 4 rows each
        float a0 = 0.f, a1 = 0.f, a2 = 0.f, a3 = 0.f;
        for (int j = 0; j < HD; ++j) {
            float pwj = pw[j * 64 + o];    // coalesced 256B/wave, L2-hit
            a0 += zt[(rg * 4 + 0) * HD + j] * pwj;
            a1 += zt[(rg * 4 + 1) * HD + j] * pwj;
            a2 += zt[(rg * 4 + 2) * HD + j] * pwj;
            a3 += zt[(rg * 4 + 3) * HD + j] * pwj;
        }
        float bo = pb[o];
        out[(size_t)(n0 + rg * 4 + 0) * 64 + o] = a0 + bo;
        out[(size_t)(n0 + rg * 4 + 1) * 64 + o] = a1 + bo;
        out[(size_t)(n0 + rg * 4 + 2) * 64 + o] = a2 + bo;
        out[(size_t)(n0 + rg * 4 + 3) * 64 + o] = a3 + bo;
    }
}

extern "C" void kernel_launch(void* const* d_in, const int* in_sizes, int n_in,
                              void* d_out, int out_size, void* d_ws, size_t ws_size,
                              hipStream_t stream) {
    const float* h    = (const float*)d_in[0];
    const int*   esrc = (const int*)d_in[1];
    const int*   edst = (const int*)d_in[2];
    const float* fc   = (const float*)d_in[3];
    const float* al   = (const float*)d_in[4];
    const float* ar   = (const float*)d_in[5];
    const float* bias = (const float*)d_in[6];
    const float* w1   = (const float*)d_in[7];
    const float* b1   = (const float*)d_in[8];
    const float* w2   = (const float*)d_in[9];
    const float* pw   = (const float*)d_in[10];
    const float* pb   = (const float*)d_in[11];
    float* out   = (float*)d_out;
    float* atten = out + (size_t)NN * OUTF;

    char* ws = (char*)d_ws;
    size_t off = 0;
    auto alloc = [&](size_t bytes) {
        void* p = ws + off;
        off = (off + bytes + 255) & ~(size_t)255;
        return p;
    };
    unsigned short* zpb   = (unsigned short*)alloc(sizeof(short) * (size_t)NN * PP * HD);  // 24 MB
    unsigned short* featb = (unsigned short*)alloc(sizeof(short) * (size_t)PP * NN * HD);  // 24 MB
    unsigned short* hb  = (unsigned short*)alloc(sizeof(short) * (size_t)NN * INF_);       // 4 MB
    unsigned short* fcT = (unsigned short*)alloc(sizeof(short) * (size_t)PP * HD * INF_);  // 768 KB
    float*  el      = (float*)alloc(sizeof(float) * PP * NN * HEADS);
    float*  er      = (float*)alloc(sizeof(float) * PP * NN * HEADS);
    float*  alpha   = (float*)alloc(sizeof(float) * (size_t)PP * NE);       // 3 MB (dst-sorted)
    int*    counts  = (int*)alloc(sizeof(int) * 3 * DOFF);                  // 384 KB
    float*  wsum    = (float*)alloc(sizeof(float) * 3 * 64);                // right after counts
    int*    offsets = (int*)alloc(sizeof(int) * 3 * POFF);
    int*    cursor  = (int*)alloc(sizeof(int) * 3 * DOFF);
    int*    ssrc_sorted = (int*)alloc(sizeof(int) * (size_t)PP * NE);       // 3 MB (dst CSR: src vals)
    float*  vbuf    = (float*)alloc(sizeof(float) * (HD + 1));

    // zero counts (3 bucketed segs) + wsum bins in one memset
    (void)hipMemsetAsync(counts, 0, sizeof(int) * 3 * DOFF + 1024, stream);

    // casts + bucketed dst histogram + atten zeroing (edges int4-vectorized)
    cast_count<<<2048 + 1536 + 768 + 1024, 256, 0, stream>>>(
        h, fc, esrc, edst, hb, fcT, counts, atten);

    // scans (3 bucketed dst segs) + collapsed semantic vector
    scan_vw<<<4, 1024, 0, stream>>>(counts, offsets, cursor, w1, b1, w2, vbuf);

    // MERGED: CSR scatter (3072 blocks) + feat GEMM (3072 blocks) — independent
    scatter_gemm<<<6144, 256, 0, stream>>>(
        esrc, edst, cursor, ssrc_sorted,
        hb, fcT, al, ar, featb, el, er);

    // fused edge-softmax + aggregation + elu + semantic-w partials (XCD-swizzled)
    fused_attn_rst<<<NN * PP / 4, 256, 0, stream>>>(
        ssrc_sorted, offsets, el, er, featb, bias, vbuf, alpha, zpb, wsum);

    // MERGED: atten column build + final_out (XCD-swizzled block remap)
    final_atten<<<K56_NWG, 256, 0, stream>>>(
        zpb, wsum, pw, pb, ssrc_sorted, offsets, alpha, out, atten);
}

// Round 12
// 551.233 us; speedup vs baseline: 1.1538x; 1.1538x over previous
//
#include <hip/hip_runtime.h>
#include <math.h>

#define NN    8192      // nodes
#define PP    3         // meta-paths
#define INF_  256       // input features
#define HID_  64
#define HEADS 8
#define OUTF  64
#define NE    262144    // edges per path (2^18)
#define HD    512       // HEADS*HID
#define DEGCAP 128      // multinomial(262144,8192): mean 32, max ~70; 128 is 16 sigma
// src-bucketed dst-CSR: 4 buckets of 2048 src nodes (2 MB featb/path/bucket).
// counts/cursor layout: [3 paths][NN dst][4 buckets]. NO src-CSR: atten is
// built column-wise from the dst-CSR (LDS colbuf + plain scattered stores).
// MEASURED OPTIMA (do not re-roll): NB=4 (NB=8 +28us), K4 XCD-swizzle (-51us),
// K56 UNswizzled (swizzle +83us: channel imbalance on 32KB-stride stores).
#define NB    4
#define DOFF  (NB * NN)         // per-path dst-bucket bin count
#define POFF  (NB * NN + 1)     // per-path offsets stride

typedef __attribute__((ext_vector_type(8))) short short8;
typedef __attribute__((ext_vector_type(4))) float f32x4;

// round-to-nearest-even fp32 -> bf16
__device__ __forceinline__ unsigned short f2bf(float f) {
    unsigned u = __float_as_uint(f);
    unsigned r = u + 0x7fffu + ((u >> 16) & 1u);
    return (unsigned short)(r >> 16);
}
__device__ __forceinline__ float bf2f_lo(unsigned v) { return __uint_as_float(v << 16); }
__device__ __forceinline__ float bf2f_hi(unsigned v) { return __uint_as_float(v & 0xffff0000u); }

// beta from wsum bins — register-only (identical fp32 sequence everywhere)
__device__ __forceinline__ void beta_reg(const float* __restrict__ wsum,
                                         float& rb0, float& rb1, float& rb2) {
    int lane = threadIdx.x & 63;
    float s0 = wsum[lane], s1 = wsum[64 + lane], s2 = wsum[128 + lane];
#pragma unroll
    for (int off = 32; off > 0; off >>= 1) {
        s0 += __shfl_down(s0, off);
        s1 += __shfl_down(s1, off);
        s2 += __shfl_down(s2, off);
    }
    float t0 = __shfl(s0, 0), t1 = __shfl(s1, 0), t2 = __shfl(s2, 0);
    float w0 = t0 / (float)NN, w1 = t1 / (float)NN, w2 = t2 / (float)NN;
    float m  = fmaxf(w0, fmaxf(w1, w2));
    float e0 = expf(w0 - m), e1 = expf(w1 - m), e2 = expf(w2 - m);
    float ss = e0 + e1 + e2;
    rb0 = e0 / ss; rb1 = e1 / ss; rb2 = e2 / ss;
}

// ---- K0: cast h->bf16, cast+transpose fc->fcT, dst-bucket histogram,
//          zero atten (256 MB NT stores, overlapped with atomic-bound blocks) ----
__global__ __launch_bounds__(256) void cast_count(
        const float* __restrict__ h, const float* __restrict__ fc,
        const int* __restrict__ esrc, const int* __restrict__ edst,
        unsigned short* __restrict__ hb, unsigned short* __restrict__ fcT,
        int* __restrict__ counts /* [3][NN][NB] */,
        float* __restrict__ atten) {
    int b = blockIdx.x, t = threadIdx.x;
    if (b < 2048) {                               // h: 2M elems, float4
        int i = b * 256 + t;
        float4 v = *(const float4*)(h + (size_t)i * 4);
        ushort4 o = { f2bf(v.x), f2bf(v.y), f2bf(v.z), f2bf(v.w) };
        *(ushort4*)(hb + (size_t)i * 4) = o;
    } else if (b < 2048 + 1536) {                 // fc: 393216 elems, transpose
        int i = (b - 2048) * 256 + t;
        if (i < PP * INF_ * HD) {
            int p = i / (INF_ * HD);
            int rem = i - p * INF_ * HD;
            int k = rem / HD;
            int n = rem - k * HD;
            fcT[(size_t)p * HD * INF_ + (size_t)n * INF_ + k] = f2bf(fc[i]);
        }
    } else if (b < 2048 + 1536 + 768) {           // edges: 4/thread, int4 loads
        int i = (b - 3584) * 256 + t;             // < 196608 (= PP*NE/4)
        int4 s4 = ((const int4*)esrc)[i];
        int4 d4 = ((const int4*)edst)[i];
        int p = i >> 16;                          // 65536 int4-groups per path
        int base = p * DOFF;
        atomicAdd(&counts[base + (d4.x << 2) + (s4.x >> 11)], 1);
        atomicAdd(&counts[base + (d4.y << 2) + (s4.y >> 11)], 1);
        atomicAdd(&counts[base + (d4.z << 2) + (s4.z >> 11)], 1);
        atomicAdd(&counts[base + (d4.w << 2) + (s4.w >> 11)], 1);
    } else {                                      // zero atten: 1024 blocks
        f32x4* a4 = (f32x4*)atten;                // 16777216 f32x4 total
        int idx0 = (b - 4352) * 256 + t;          // [0, 262144)
        f32x4 zero = {0.f, 0.f, 0.f, 0.f};
#pragma unroll 4
        for (int it = 0; it < 64; ++it)
            __builtin_nontemporal_store(zero, &a4[(size_t)it * 262144 + idx0]);
    }
}

// ---- K1: exclusive scans — blocks 0..2: dst-bucketed (32768 bins, 32/thread);
//          block 3: collapsed semantic vec ----
__global__ __launch_bounds__(1024) void scan_vw(
        const int* __restrict__ counts, int* __restrict__ offsets,
        int* __restrict__ cursor, const float* __restrict__ w1,
        const float* __restrict__ b1, const float* __restrict__ w2,
        float* __restrict__ v /* [513] */) {
    int t = threadIdx.x;
    if (blockIdx.x == 3) {
        if (t < HD) {
            float s = 0.f;
            for (int k = 0; k < 128; ++k) s += w1[t * 128 + k] * w2[k];
            v[t] = s;
        } else if (t == HD) {
            float c = 0.f;
            for (int k = 0; k < 128; ++k) c += b1[k] * w2[k];
            v[HD] = c;
        }
        return;
    }
    __shared__ int sh[1024];
    // dst-bucketed segment for path seg: 4*NN bins, 32 per thread
    int seg = blockIdx.x;
    const int* cnt = counts + seg * DOFF;
    int* offs = offsets + seg * POFF;
    int* cur  = cursor + seg * DOFF;
    int loc[32];
    int s = 0;
#pragma unroll
    for (int i = 0; i < 32; ++i) { loc[i] = cnt[t * 32 + i]; s += loc[i]; }
    sh[t] = s;
    __syncthreads();
    for (int off = 1; off < 1024; off <<= 1) {
        int vv = (t >= off) ? sh[t - off] : 0;
        __syncthreads();
        sh[t] += vv;
        __syncthreads();
    }
    int run = sh[t] - s;
#pragma unroll
    for (int i = 0; i < 32; ++i) {
        offs[t * 32 + i] = run;
        cur[t * 32 + i]  = run;
        run += loc[i];
    }
    if (t == 1023) offs[DOFF] = run;
}

// ---- K23: MERGED scatter (blocks 0..3071) + feat GEMM (blocks 3072..6143) ----
// Scatter: 1 global atomic + 1 store per edge (measured-cheap at this
// parallelism; R7's serial atomic-free variant was 4x worse).
#define LDK 72   // padded LDS row stride (bf16)
__global__ __launch_bounds__(256) void scatter_gemm(
        const int* __restrict__ esrc, const int* __restrict__ edst,
        int* __restrict__ cursor, int* __restrict__ ssrc_sorted,
        const unsigned short* __restrict__ hb,   // [NN, INF_] bf16
        const unsigned short* __restrict__ fcT,  // [PP, HD, INF_] bf16
        const float* __restrict__ al_all,        // [PP, HD]
        const float* __restrict__ ar_all,        // [PP, HD]
        unsigned short* __restrict__ featb,      // [PP, NN, HD] bf16
        float* __restrict__ el,                  // [PP, NN, HEADS]
        float* __restrict__ er) {
    __shared__ unsigned short As[64 * LDK];
    __shared__ unsigned short Bs[64 * LDK];
    int tid = threadIdx.x;
    if (blockIdx.x < 3072) {
        // ---- scatter role: bucketed dst-CSR (src values) ----
        int i = blockIdx.x * 256 + tid;          // exactly PP*NE threads
        int p = i >> 18;
        int s = esrc[i], d = edst[i];
        int pos = atomicAdd(&cursor[p * DOFF + (d << 2) + (s >> 11)], 1);
        ssrc_sorted[(size_t)p * NE + pos] = s;
        return;
    }
    // ---- GEMM role: feat[p] = h @ fc_p via bf16 MFMA; K-stage 64 ----
    int g  = blockIdx.x - 3072;                  // 0..3071
    int p  = g >> 10;                            // 1024 blocks per path
    int n0 = (g & 7) * 64;
    int m0 = ((g >> 3) & 127) * 64;
    const unsigned short* Bt = fcT + (size_t)p * HD * INF_;
    unsigned short* C = featb + (size_t)p * NN * HD;
    int wv   = tid >> 6, lane = tid & 63;
    int row  = tid >> 2, kc = (tid & 3) * 8;     // staging: 64 rows x 32 k (x2 chunks)
    int l16  = lane & 15, quad = lane >> 4;
    int mw   = wv * 16;
    f32x4 acc[4] = {{0.f,0.f,0.f,0.f},{0.f,0.f,0.f,0.f},
                    {0.f,0.f,0.f,0.f},{0.f,0.f,0.f,0.f}};
    for (int k0 = 0; k0 < INF_; k0 += 64) {
        const unsigned short* ha = &hb[(size_t)(m0 + row) * INF_ + k0 + kc];
        const unsigned short* ba = &Bt[(size_t)(n0 + row) * INF_ + k0 + kc];
        *(short8*)&As[row * LDK + kc]      = *(const short8*)ha;
        *(short8*)&As[row * LDK + kc + 32] = *(const short8*)(ha + 32);
        *(short8*)&Bs[row * LDK + kc]      = *(const short8*)ba;
        *(short8*)&Bs[row * LDK + kc + 32] = *(const short8*)(ba + 32);
        __syncthreads();
        short8 af0 = *(short8*)&As[(mw + l16) * LDK + quad * 8];
        short8 af1 = *(short8*)&As[(mw + l16) * LDK + 32 + quad * 8];
#pragma unroll
        for (int nt = 0; nt < 4; ++nt) {
            short8 bf0 = *(short8*)&Bs[(nt * 16 + l16) * LDK + quad * 8];
            acc[nt] = __builtin_amdgcn_mfma_f32_16x16x32_bf16(af0, bf0, acc[nt], 0, 0, 0);
            short8 bf1 = *(short8*)&Bs[(nt * 16 + l16) * LDK + 32 + quad * 8];
            acc[nt] = __builtin_amdgcn_mfma_f32_16x16x32_bf16(af1, bf1, acc[nt], 0, 0, 0);
        }
        __syncthreads();
    }
    // D layout: col = nt*16 + l16, row = mw + quad*4 + r
#pragma unroll
    for (int nt = 0; nt < 4; ++nt) {
#pragma unroll
        for (int r = 0; r < 4; ++r) {
            C[(size_t)(m0 + mw + quad * 4 + r) * HD + n0 + nt * 16 + l16] =
                f2bf(acc[nt][r]);
        }
    }
    // fused el/er: head h = n0/64 fully contained in this block's n-tile
    int hidx = n0 >> 6;
    float alv[4], arv[4];
#pragma unroll
    for (int nt = 0; nt < 4; ++nt) {
        alv[nt] = al_all[p * HD + n0 + nt * 16 + l16];
        arv[nt] = ar_all[p * HD + n0 + nt * 16 + l16];
    }
    float* elp = el + (size_t)p * NN * HEADS;
    float* erp = er + (size_t)p * NN * HEADS;
#pragma unroll
    for (int r = 0; r < 4; ++r) {
        float pe = acc[0][r] * alv[0] + acc[1][r] * alv[1] +
                   acc[2][r] * alv[2] + acc[3][r] * alv[3];
        float pr = acc[0][r] * arv[0] + acc[1][r] * arv[1] +
                   acc[2][r] * arv[2] + acc[3][r] * arv[3];
#pragma unroll
        for (int m = 1; m < 16; m <<= 1) {
            pe += __shfl_xor(pe, m);
            pr += __shfl_xor(pr, m);
        }
        if (l16 == 0) {
            int node = m0 + mw + quad * 4 + r;
            elp[node * HEADS + hidx] = pe;
            erp[node * HEADS + hidx] = pr;
        }
    }
}

// ---- K4: FUSED edge softmax + aggregation, ONE WAVE PER (dst,p) ----
// XCD-aware swizzle: each XCD owns a contiguous gid range, so its waves walk
// the same featb bucket slice together -> slice stays in that XCD's 4MB L2.
__global__ __launch_bounds__(256) void fused_attn_rst(
        const int* __restrict__ ssrc_sorted, const int* __restrict__ offsets_all,
        const float* __restrict__ el, const float* __restrict__ er,
        const unsigned short* __restrict__ featb,
        const float* __restrict__ bias_all, const float* __restrict__ v,
        float* __restrict__ alpha_all /* dst-sorted order */,
        unsigned short* __restrict__ zpb,
        float* __restrict__ wsum /* [3][64] bins */) {
    __shared__ float sh_e[4][DEGCAP * 8];
    __shared__ int   sh_src[4][DEGCAP];
    int wv = threadIdx.x >> 6, lane = threadIdx.x & 63;
    // bijective XCD swizzle: nwg = 6144 = 8 * 768
    int swz = (blockIdx.x & 7) * 768 + (blockIdx.x >> 3);
    int gid = swz * 4 + wv;                // over NN*PP
    int n = gid & (NN - 1);
    int p = gid >> 13;                     // NN = 2^13
    const int* srcrow  = ssrc_sorted + (size_t)p * NE;
    const int* offs    = offsets_all + p * POFF;
    const float* elp   = el + (size_t)p * NN * HEADS;
    const float* erp   = er + (size_t)p * NN * HEADS;
    const unsigned short* feat = featb + (size_t)p * NN * HD;
    int start = offs[n * NB];
    int deg = offs[n * NB + NB] - start;   // whole (4-bucket) list for dst n
    if (deg > DEGCAP) deg = DEGCAP;        // 16-sigma safe

    // Phase A: one sequential src read per edge; leaky-relu scores into LDS
    float4 r0 = *(const float4*)(erp + n * 8);
    float4 r1 = *(const float4*)(erp + n * 8 + 4);
    for (int t = lane; t < deg; t += 64) {
        int s = srcrow[start + t];
        sh_src[wv][t] = s;
        float4 l0 = *(const float4*)(elp + s * 8);
        float4 l1 = *(const float4*)(elp + s * 8 + 4);
        float sc[8] = {l0.x + r0.x, l0.y + r0.y, l0.z + r0.z, l0.w + r0.w,
                       l1.x + r1.x, l1.y + r1.y, l1.z + r1.z, l1.w + r1.w};
#pragma unroll
        for (int hh = 0; hh < 8; ++hh) {
            float x = sc[hh];
            sh_e[wv][t * 8 + hh] = x > 0.f ? x : 0.2f * x;
        }
    }
    __syncthreads();

    // Phase B: per-head softmax; 8 lanes per head (h = lane>>3, j = lane&7)
    int h = lane >> 3;
    {
        int j = lane & 7;
        float m = -INFINITY;
        for (int t = j; t < deg; t += 8) m = fmaxf(m, sh_e[wv][t * 8 + h]);
#pragma unroll
        for (int off = 4; off; off >>= 1) m = fmaxf(m, __shfl_xor(m, off));
        float ssum = 0.f;
        for (int t = j; t < deg; t += 8) {
            float ee = __expf(sh_e[wv][t * 8 + h] - m);
            sh_e[wv][t * 8 + h] = ee;
            ssum += ee;
        }
#pragma unroll
        for (int off = 4; off; off >>= 1) ssum += __shfl_xor(ssum, off);
        float inv = 1.f / ssum;
        for (int t = j; t < deg; t += 8) sh_e[wv][t * 8 + h] *= inv;
    }
    __syncthreads();

    // Phase C: alpha = mean over heads — fully coalesced write
    for (int t = lane; t < deg; t += 64) {
        float s = 0.f;
#pragma unroll
        for (int hh = 0; hh < 8; ++hh) s += sh_e[wv][t * 8 + hh];
        alpha_all[(size_t)p * NE + start + t] = s * 0.125f;
    }

    // Phase D: lane covers cols c..c+7 (head h); one 16B load per edge row.
    int c = lane * 8;
    float acc[8] = {0.f, 0.f, 0.f, 0.f, 0.f, 0.f, 0.f, 0.f};
#define FMA8(F, KI) { \
        float a_ = sh_e[wv][(KI) * 8 + h]; \
        acc[0] += a_ * bf2f_lo((F).x); acc[1] += a_ * bf2f_hi((F).x); \
        acc[2] += a_ * bf2f_lo((F).y); acc[3] += a_ * bf2f_hi((F).y); \
        acc[4] += a_ * bf2f_lo((F).z); acc[5] += a_ * bf2f_hi((F).z); \
        acc[6] += a_ * bf2f_lo((F).w); acc[7] += a_ * bf2f_hi((F).w); }
    int k = 0;
    for (; k + 4 <= deg; k += 4) {
        int s0 = sh_src[wv][k],     s1 = sh_src[wv][k + 1];
        int s2 = sh_src[wv][k + 2], s3 = sh_src[wv][k + 3];
        uint4 f0 = *(const uint4*)&feat[(size_t)s0 * HD + c];
        uint4 f1 = *(const uint4*)&feat[(size_t)s1 * HD + c];
        uint4 f2 = *(const uint4*)&feat[(size_t)s2 * HD + c];
        uint4 f3 = *(const uint4*)&feat[(size_t)s3 * HD + c];
        FMA8(f0, k); FMA8(f1, k + 1); FMA8(f2, k + 2); FMA8(f3, k + 3);
    }
    for (; k < deg; ++k) {
        int s = sh_src[wv][k];
        uint4 f = *(const uint4*)&feat[(size_t)s * HD + c];
        FMA8(f, k);
    }
#undef FMA8
    const float* bias = bias_all + p * HD;
    float4 b0 = *(const float4*)(bias + c);
    float4 b1 = *(const float4*)(bias + c + 4);
    float z[8];
    z[0] = acc[0] + b0.x; z[1] = acc[1] + b0.y; z[2] = acc[2] + b0.z; z[3] = acc[3] + b0.w;
    z[4] = acc[4] + b1.x; z[5] = acc[5] + b1.y; z[6] = acc[6] + b1.z; z[7] = acc[7] + b1.w;
#pragma unroll
    for (int i = 0; i < 8; ++i) z[i] = z[i] > 0.f ? z[i] : expm1f(z[i]);
    uint4 zo;
    zo.x = (unsigned)f2bf(z[0]) | ((unsigned)f2bf(z[1]) << 16);
    zo.y = (unsigned)f2bf(z[2]) | ((unsigned)f2bf(z[3]) << 16);
    zo.z = (unsigned)f2bf(z[4]) | ((unsigned)f2bf(z[5]) << 16);
    zo.w = (unsigned)f2bf(z[6]) | ((unsigned)f2bf(z[7]) << 16);
    *(uint4*)&zpb[(size_t)n * (PP * HD) + p * HD + c] = zo;

    // Phase E: semantic-attention partial — wave-reduce dot(z, v)
    float4 v0 = *(const float4*)(v + c);
    float4 v1 = *(const float4*)(v + c + 4);
    float part = z[0] * v0.x + z[1] * v0.y + z[2] * v0.z + z[3] * v0.w +
                 z[4] * v1.x + z[5] * v1.y + z[6] * v1.z + z[7] * v1.w;
#pragma unroll
    for (int off = 32; off > 0; off >>= 1) part += __shfl_down(part, off);
    if (lane == 0) {
        float w = part + v[HD];             // + c0
        w = w > 0.f ? w : 0.01f * w;        // leaky_relu 0.01 BEFORE mean
        atomicAdd(&wsum[p * 64 + (n & 63)], w);
    }
}

// ---- K56: atten COLUMN build (blocks 0..8191) + final_out (8192..8703) ----
// Column block n: accumulate all 3 paths' edges into LDS colbuf (LDS atomics
// handle duplicates), then ONE PLAIN scattered 4B store per edge — duplicates
// re-store the same summed value (race-free). No global atomics, no src-CSR.
// NO XCD swizzle here: default round-robin stripes the 32KB-stride scattered
// stores across all HBM channels (swizzle caused channel imbalance, +83us).
#define K5R 16
__global__ __launch_bounds__(256) void final_atten(
        const unsigned short* __restrict__ zpb, const float* __restrict__ wsum,
        const float* __restrict__ pw, const float* __restrict__ pb,
        const int* __restrict__ ssrc_sorted, const int* __restrict__ offsets_all,
        const float* __restrict__ alpha,
        float* __restrict__ out, float* __restrict__ atten) {
    __shared__ float buf[NN];          // 32 KB: colbuf (atten) or zt (out role)
    __shared__ int   sh_s[3 * DEGCAP];
    __shared__ int   sh_cnt;
    float b0, b1, b2;
    beta_reg(wsum, b0, b1, b2);
    int tid = threadIdx.x;
    if (blockIdx.x < NN) {
        // ---- atten-column role: dst n, all 3 paths ----
        int n = blockIdx.x;
        f32x4 zero = {0.f, 0.f, 0.f, 0.f};
        for (int j = tid; j < NN / 4; j += 256) ((f32x4*)buf)[j] = zero;
        if (tid == 0) sh_cnt = 0;
        __syncthreads();
        for (int p = 0; p < PP; ++p) {
            float bsel = p == 0 ? b0 : (p == 1 ? b1 : b2);
            const int* offs = offsets_all + p * POFF;
            int start = offs[n * NB];
            int deg = offs[n * NB + NB] - start;
            if (deg > DEGCAP) deg = DEGCAP;
            const int* srcrow = ssrc_sorted + (size_t)p * NE + start;   // sequential
            const float* arow = alpha + (size_t)p * NE + start;         // sequential
            for (int t = tid; t < deg; t += 256) {
                int s = srcrow[t];
                atomicAdd(&buf[s], arow[t] * bsel);      // LDS atomic (cheap)
                int slot = atomicAdd(&sh_cnt, 1);        // LDS counter
                sh_s[slot] = s;
            }
        }
        __syncthreads();
        int cnt = sh_cnt;
        for (int k = tid; k < cnt; k += 256) {
            int s = sh_s[k];
            __builtin_nontemporal_store(buf[s], &atten[(size_t)s * NN + n]);
        }
    } else {
        // ---- final_out role: 16 rows/block, pred_w streamed once per block ----
        float* zt = buf;                   // [K5R][HD] row-major
        int n0 = (blockIdx.x - NN) * K5R;
        int c = tid * 2;
#pragma unroll
        for (int r = 0; r < K5R; ++r) {
            const unsigned short* zr = zpb + (size_t)(n0 + r) * (PP * HD);
            unsigned u0 = *(const unsigned*)(zr + c);
            unsigned u1 = *(const unsigned*)(zr + HD + c);
            unsigned u2 = *(const unsigned*)(zr + 2 * HD + c);
            zt[r * HD + c]     = b0 * bf2f_lo(u0) + b1 * bf2f_lo(u1) + b2 * bf2f_lo(u2);
            zt[r * HD + c + 1] = b0 * bf2f_hi(u0) + b1 * bf2f_hi(u1) + b2 * bf2f_hi(u2);
        }
        __syncthreads();
        int o = tid & 63, rg = tid >> 6;   // 4 row-groups x 4 rows each
        float a0 = 0.f, a1 = 0.f, a2 = 0.f, a3 = 0.f;
        for (int j = 0; j < HD; ++j) {
            float pwj = pw[j * 64 + o];    // coalesced 256B/wave, L2-hit
            a0 += zt[(rg * 4 + 0) * HD + j] * pwj;
            a1 += zt[(rg * 4 + 1) * HD + j] * pwj;
            a2 += zt[(rg * 4 + 2) * HD + j] * pwj;
            a3 += zt[(rg * 4 + 3) * HD + j] * pwj;
        }
        float bo = pb[o];
        out[(size_t)(n0 + rg * 4 + 0) * 64 + o] = a0 + bo;
        out[(size_t)(n0 + rg * 4 + 1) * 64 + o] = a1 + bo;
        out[(size_t)(n0 + rg * 4 + 2) * 64 + o] = a2 + bo;
        out[(size_t)(n0 + rg * 4 + 3) * 64 + o] = a3 + bo;
    }
}

extern "C" void kernel_launch(void* const* d_in, const int* in_sizes, int n_in,
                              void* d_out, int out_size, void* d_ws, size_t ws_size,
                              hipStream_t stream) {
    const float* h    = (const float*)d_in[0];
    const int*   esrc = (const int*)d_in[1];
    const int*   edst = (const int*)d_in[2];
    const float* fc   = (const float*)d_in[3];
    const float* al   = (const float*)d_in[4];
    const float* ar   = (const float*)d_in[5];
    const float* bias = (const float*)d_in[6];
    const float* w1   = (const float*)d_in[7];
    const float* b1   = (const float*)d_in[8];
    const float* w2   = (const float*)d_in[9];
    const float* pw   = (const float*)d_in[10];
    const float* pb   = (const float*)d_in[11];
    float* out   = (float*)d_out;
    float* atten = out + (size_t)NN * OUTF;

    char* ws = (char*)d_ws;
    size_t off = 0;
    auto alloc = [&](size_t bytes) {
        void* p = ws + off;
        off = (off + bytes + 255) & ~(size_t)255;
        return p;
    };
    unsigned short* zpb   = (unsigned short*)alloc(sizeof(short) * (size_t)NN * PP * HD);  // 24 MB
    unsigned short* featb = (unsigned short*)alloc(sizeof(short) * (size_t)PP * NN * HD);  // 24 MB
    unsigned short* hb  = (unsigned short*)alloc(sizeof(short) * (size_t)NN * INF_);       // 4 MB
    unsigned short* fcT = (unsigned short*)alloc(sizeof(short) * (size_t)PP * HD * INF_);  // 768 KB
    float*  el      = (float*)alloc(sizeof(float) * PP * NN * HEADS);
    float*  er      = (float*)alloc(sizeof(float) * PP * NN * HEADS);
    float*  alpha   = (float*)alloc(sizeof(float) * (size_t)PP * NE);       // 3 MB (dst-sorted)
    int*    counts  = (int*)alloc(sizeof(int) * 3 * DOFF);                  // 384 KB
    float*  wsum    = (float*)alloc(sizeof(float) * 3 * 64);                // right after counts
    int*    offsets = (int*)alloc(sizeof(int) * 3 * POFF);
    int*    cursor  = (int*)alloc(sizeof(int) * 3 * DOFF);
    int*    ssrc_sorted = (int*)alloc(sizeof(int) * (size_t)PP * NE);       // 3 MB (dst CSR: src vals)
    float*  vbuf    = (float*)alloc(sizeof(float) * (HD + 1));

    // zero counts (3 bucketed segs) + wsum bins in one memset
    (void)hipMemsetAsync(counts, 0, sizeof(int) * 3 * DOFF + 1024, stream);

    // casts + bucketed dst histogram + atten zeroing (edges int4-vectorized)
    cast_count<<<2048 + 1536 + 768 + 1024, 256, 0, stream>>>(
        h, fc, esrc, edst, hb, fcT, counts, atten);

    // scans (3 bucketed dst segs) + collapsed semantic vector
    scan_vw<<<4, 1024, 0, stream>>>(counts, offsets, cursor, w1, b1, w2, vbuf);

    // MERGED: CSR scatter (3072 blocks) + feat GEMM (3072 blocks) — independent
    scatter_gemm<<<6144, 256, 0, stream>>>(
        esrc, edst, cursor, ssrc_sorted,
        hb, fcT, al, ar, featb, el, er);

    // fused edge-softmax + aggregation + elu + semantic-w partials (XCD-swizzled)
    fused_attn_rst<<<NN * PP / 4, 256, 0, stream>>>(
        ssrc_sorted, offsets, el, er, featb, bias, vbuf, alpha, zpb, wsum);

    // MERGED: atten column build (8192 blocks) + final_out (512 blocks)
    final_atten<<<NN + NN / K5R, 256, 0, stream>>>(
        zpb, wsum, pw, pb, ssrc_sorted, offsets, alpha, out, atten);
}